// Round 1
// baseline (799.021 us; speedup 1.0000x reference)
//
#include <hip/hip_runtime.h>
#include <math.h>

#define H 128
#define KN 16
#define NN 16384   // N per batch

__device__ __forceinline__ float silu_f(float v) {
    return v / (1.0f + __expf(-v));
}

// Kernel 1: per-node precompute
//   A[i][c]  = sum_k h[i][k] * We1[k][c]       + be1[c]
//   Bm[i][c] = sum_k h[i][k] * We1[128+k][c]
// 8 nodes per block, 256 threads: thread = one output column (0..255).
__global__ __launch_bounds__(256) void precompute_ab(
    const float* __restrict__ h, const float* __restrict__ We1,
    const float* __restrict__ be1, float* __restrict__ A, float* __restrict__ Bm)
{
    __shared__ float hsh[8 * H];
    const int i0 = blockIdx.x * 8;
    const int tid = threadIdx.x;
    for (int l = tid; l < 8 * H; l += 256) hsh[l] = h[(size_t)i0 * H + l];
    __syncthreads();

    const int c = tid;
    const float* Wp = (c < H) ? (We1 + c) : (We1 + H * H + (c - H));
    float acc[8];
#pragma unroll
    for (int n = 0; n < 8; n++) acc[n] = 0.0f;
    for (int kk = 0; kk < H; kk++) {
        float w = Wp[kk * H];
#pragma unroll
        for (int n = 0; n < 8; n++) acc[n] += hsh[n * H + kk] * w;
    }
    if (c < H) {
        float b = be1[c];
#pragma unroll
        for (int n = 0; n < 8; n++) A[(size_t)(i0 + n) * H + c] = acc[n] + b;
    } else {
        int cc = c - H;
#pragma unroll
        for (int n = 0; n < 8; n++) Bm[(size_t)(i0 + n) * H + cc] = acc[n];
    }
}

// 64x128 = LDSin(64xH) @ W(HxH row-major) + bias, optional silu, write LDSout.
// 256 threads: thread owns 8 rows x 4 cols. Each LDS read of `in` feeds 4 FMAs.
__device__ __forceinline__ void gemm64_tile(
    const float* in, const float* __restrict__ W, const float* __restrict__ bias,
    float* out, bool do_silu, int tid)
{
    const int c0 = (tid & 31) * 4;
    const int r0 = (tid >> 5) * 8;
    float4 bb = *(const float4*)(bias + c0);
    float acc[8][4];
#pragma unroll
    for (int rr = 0; rr < 8; rr++) {
        acc[rr][0] = bb.x; acc[rr][1] = bb.y; acc[rr][2] = bb.z; acc[rr][3] = bb.w;
    }
    for (int kk = 0; kk < H; kk++) {
        float4 w = *(const float4*)(W + kk * H + c0);
#pragma unroll
        for (int rr = 0; rr < 8; rr++) {
            float tv = in[(r0 + rr) * H + kk];
            acc[rr][0] += tv * w.x;
            acc[rr][1] += tv * w.y;
            acc[rr][2] += tv * w.z;
            acc[rr][3] += tv * w.w;
        }
    }
#pragma unroll
    for (int rr = 0; rr < 8; rr++) {
        float4 o;
        if (do_silu) {
            o.x = silu_f(acc[rr][0]); o.y = silu_f(acc[rr][1]);
            o.z = silu_f(acc[rr][2]); o.w = silu_f(acc[rr][3]);
        } else {
            o.x = acc[rr][0]; o.y = acc[rr][1]; o.z = acc[rr][2]; o.w = acc[rr][3];
        }
        *(float4*)(out + (r0 + rr) * H + c0) = o;
    }
}

// Kernel 2: fused edge + node computation. 4 nodes (64 edges) per block, 256 threads.
__global__ __launch_bounds__(256) void egnn_fused(
    const float* __restrict__ h, const float* __restrict__ x,
    const int* __restrict__ edge_idx,
    const float* __restrict__ A, const float* __restrict__ Bm,
    const float* __restrict__ We1,
    const float* __restrict__ We2, const float* __restrict__ be2,
    const float* __restrict__ Wc1, const float* __restrict__ bc1,
    const float* __restrict__ Wc2,
    const float* __restrict__ Wn1, const float* __restrict__ bn1,
    const float* __restrict__ Wn2, const float* __restrict__ bn2,
    float* __restrict__ out, int BN)
{
    __shared__ float tbuf[64 * H];   // t, then c1, then u (reused)
    __shared__ float mbuf[64 * H];   // m_ij
    __shared__ float Ash[4 * H];
    __shared__ float hsh[4 * H];
    __shared__ float msum[4 * H];
    __shared__ float sqd[64];
    __shared__ float cwv[64];
    __shared__ float xd[64 * 3];
    __shared__ int   jgs[64];

    const int i0 = blockIdx.x * 4;
    const int tid = threadIdx.x;

    // P0: stage h rows, A rows, edge geometry
    for (int l = tid; l < 4 * H; l += 256) {
        hsh[l] = h[(size_t)i0 * H + l];
        Ash[l] = A[(size_t)i0 * H + l];
    }
    if (tid < 64) {
        int e = tid;
        int nd = e >> 4;
        int i = i0 + nd;
        int b = i / NN;
        int jl = edge_idx[(size_t)i * KN + (e & 15)];
        int j = b * NN + jl;
        jgs[e] = j;
        float d0 = x[i * 3 + 0] - x[j * 3 + 0];
        float d1 = x[i * 3 + 1] - x[j * 3 + 1];
        float d2 = x[i * 3 + 2] - x[j * 3 + 2];
        xd[e * 3 + 0] = d0; xd[e * 3 + 1] = d1; xd[e * 3 + 2] = d2;
        sqd[e] = d0 * d0 + d1 * d1 + d2 * d2;
    }
    __syncthreads();

    // P1: t = silu(A[i] + Bm[j] + sqd*We1[256] )  (be1 already inside A)
    {
        const int c = tid & (H - 1);
        const int half = tid >> 7;                  // 0..1
        const float w256c = We1[256 * H + c];
#pragma unroll 4
        for (int r = half * 32; r < half * 32 + 32; r++) {
            int nd = r >> 4;
            float t = Ash[nd * H + c] + Bm[(size_t)jgs[r] * H + c] + sqd[r] * w256c;
            tbuf[r * H + c] = silu_f(t);
        }
    }
    __syncthreads();

    // P2: m = silu(t @ We2 + be2)
    gemm64_tile(tbuf, We2, be2, mbuf, true, tid);
    __syncthreads();

    // P3: c1 = silu(m @ Wc1 + bc1)  -> reuse tbuf
    gemm64_tile(mbuf, Wc1, bc1, tbuf, true, tid);
    __syncthreads();

    // P4: cw[e] = dot(c1[e], Wc2)   (staggered kk start to avoid bank conflicts)
    if (tid < 64) {
        int e = tid;
        float acc = 0.0f;
        for (int s = 0; s < H; s++) {
            int kk = (e + s) & (H - 1);
            acc += tbuf[e * H + kk] * Wc2[kk];
        }
        cwv[e] = acc;
    }
    __syncthreads();

    // P5: msum[nd][c] = sum_k mbuf[nd*16+k][c]
    {
        const int c = tid & (H - 1);
        const int g = tid >> 7;
#pragma unroll
        for (int rep = 0; rep < 2; rep++) {
            int nd = g + rep * 2;
            float s = 0.0f;
#pragma unroll
            for (int kk = 0; kk < KN; kk++) s += mbuf[(nd * KN + kk) * H + c];
            msum[nd * H + c] = s;
        }
    }
    __syncthreads();

    // P6: u = silu([h, m_i] @ Wn1 + bn1)  -> store in tbuf rows 0..3
    {
        const int c = tid & (H - 1);
        const int g = tid >> 7;
        float acc0 = bn1[c], acc1 = bn1[c];
        for (int kk = 0; kk < H; kk++) {
            float w = Wn1[kk * H + c];
            acc0 += hsh[g * H + kk] * w;
            acc1 += hsh[(g + 2) * H + kk] * w;
        }
        for (int kk = 0; kk < H; kk++) {
            float w = Wn1[(H + kk) * H + c];
            acc0 += msum[g * H + kk] * w;
            acc1 += msum[(g + 2) * H + kk] * w;
        }
        tbuf[g * H + c] = silu_f(acc0);
        tbuf[(g + 2) * H + c] = silu_f(acc1);
    }
    __syncthreads();

    // P7: h_new = u @ Wn2 + bn2 + h
    {
        const int c = tid & (H - 1);
        const int g = tid >> 7;
        float a0 = bn2[c] + hsh[g * H + c];
        float a1 = bn2[c] + hsh[(g + 2) * H + c];
        for (int kk = 0; kk < H; kk++) {
            float w = Wn2[kk * H + c];
            a0 += tbuf[g * H + kk] * w;
            a1 += tbuf[(g + 2) * H + kk] * w;
        }
        out[(size_t)(i0 + g) * H + c] = a0;
        out[(size_t)(i0 + g + 2) * H + c] = a1;
    }

    // P8: x_new = x + mean_k(x_diff * cw)
    if (tid < 12) {
        int nd = tid / 3, d = tid % 3;
        float s = 0.0f;
#pragma unroll
        for (int k = 0; k < KN; k++) {
            int e = nd * KN + k;
            s += xd[e * 3 + d] * cwv[e];
        }
        int i = i0 + nd;
        out[(size_t)BN * H + i * 3 + d] = x[i * 3 + d] + s * (1.0f / (float)KN);
    }
}

extern "C" void kernel_launch(void* const* d_in, const int* in_sizes, int n_in,
                              void* d_out, int out_size, void* d_ws, size_t ws_size,
                              hipStream_t stream) {
    const float* h       = (const float*)d_in[0];
    const float* x       = (const float*)d_in[1];
    const int*   edge_idx= (const int*)d_in[2];
    const float* We1     = (const float*)d_in[3];
    const float* be1     = (const float*)d_in[4];
    const float* We2     = (const float*)d_in[5];
    const float* be2     = (const float*)d_in[6];
    const float* Wc1     = (const float*)d_in[7];
    const float* bc1     = (const float*)d_in[8];
    const float* Wc2     = (const float*)d_in[9];
    const float* Wn1     = (const float*)d_in[10];
    const float* bn1     = (const float*)d_in[11];
    const float* Wn2     = (const float*)d_in[12];
    const float* bn2     = (const float*)d_in[13];
    float* out = (float*)d_out;

    const int BN = in_sizes[0] / H;   // B*N = 32768

    float* A  = (float*)d_ws;
    float* Bm = A + (size_t)BN * H;

    precompute_ab<<<BN / 8, 256, 0, stream>>>(h, We1, be1, A, Bm);
    egnn_fused<<<BN / 4, 256, 0, stream>>>(h, x, edge_idx, A, Bm, We1,
                                           We2, be2, Wc1, bc1, Wc2,
                                           Wn1, bn1, Wn2, bn2, out, BN);
}

// Round 2
// 127.531 us; speedup vs baseline: 6.2653x; 6.2653x over previous
//
#include <hip/hip_runtime.h>
#include <math.h>

#define H 128
#define KN 16
#define NN 16384
#define NB 8      // nodes per block (fused)
#define EB 128    // edges per block

typedef short s16x8 __attribute__((ext_vector_type(8)));
typedef float f32x4 __attribute__((ext_vector_type(4)));

__device__ __forceinline__ float b2f(ushort u){
    union { uint i; float f; } v; v.i = ((uint)u) << 16; return v.f;
}
__device__ __forceinline__ ushort f2b(float f){
    union { float f; uint i; } v; v.f = f;
    uint r = v.i + 0x7fffu + ((v.i >> 16) & 1u);
    return (ushort)(r >> 16);
}
__device__ __forceinline__ float silu_f(float v){
    float e = __expf(-v);
    return v * __builtin_amdgcn_rcpf(1.0f + e);
}

// ---------------------------------------------------------------------------
// Pack weights (transposed) into MFMA A-fragment order, fp32 -> bf16.
// A-operand assumed mapping: A[m][k], m = lane&15, k = kt*32 + 8*(lane>>4)+e.
// packed[(mt*Kt+kt)*512 + lane*8 + e] = W[k][m]   (W given as (K x M) row-major)
// frag ranges: We2T[0,32) Wc1T[32,64) Wn1T[64,128) Wn2T[128,160) W1pT[160,224)
// ---------------------------------------------------------------------------
__global__ __launch_bounds__(256) void pack_all(
    const float* __restrict__ We2, const float* __restrict__ Wc1,
    const float* __restrict__ Wn1, const float* __restrict__ Wn2,
    const float* __restrict__ We1,
    ushort* __restrict__ dWe2, ushort* __restrict__ dWc1,
    ushort* __restrict__ dWn1, ushort* __restrict__ dWn2,
    ushort* __restrict__ dW1p)
{
    int idx = blockIdx.x * 256 + threadIdx.x;
    int fid = idx >> 6, l = idx & 63;
    const float* src; ushort* dst; int Kt; int mode = 0; int lfid;
    if (fid < 32)       { src = We2; dst = dWe2; Kt = 4; lfid = fid; }
    else if (fid < 64)  { src = Wc1; dst = dWc1; Kt = 4; lfid = fid - 64 + 32 - 32; lfid = fid - 32; }
    else if (fid < 128) { src = Wn1; dst = dWn1; Kt = 8; lfid = fid - 64; }
    else if (fid < 160) { src = Wn2; dst = dWn2; Kt = 4; lfid = fid - 128; }
    else                { src = We1; dst = dW1p; Kt = 4; mode = 1; lfid = fid - 160; }
    int mt = lfid / Kt, kt = lfid % Kt;
    int m = mt * 16 + (l & 15);
    s16x8 ov;
#pragma unroll
    for (int e = 0; e < 8; e++){
        int k = kt * 32 + ((l >> 4) << 3) + e;
        float v;
        if (mode == 0) v = src[k * 128 + m];
        else           v = src[(k + ((m >= 128) ? 128 : 0)) * 128 + (m & 127)];
        ov[e] = (short)f2b(v);
    }
    *(s16x8*)(dst + (size_t)lfid * 512 + l * 8) = ov;
}

// ---------------------------------------------------------------------------
// Precompute A[i][c] = h[i]@We1[:128] + be1,  Bm[i][c] = h[i]@We1[128:256]
// via MFMA: ABt = W1p^T @ h^T.  64 nodes/block, 4 waves, wave w: mt 4w..4w+3.
// ---------------------------------------------------------------------------
__global__ __launch_bounds__(256) void precompute_mfma(
    const float* __restrict__ h, const float* __restrict__ be1,
    const ushort* __restrict__ W1p,
    ushort* __restrict__ A, ushort* __restrict__ Bm)
{
    const int tid = threadIdx.x;
    const int w = tid >> 6, l = tid & 63, lg = l >> 4, li = l & 15;
    const int i0 = blockIdx.x * 64;

    f32x4 acc[4][4];
#pragma unroll
    for (int a = 0; a < 4; a++)
#pragma unroll
        for (int b = 0; b < 4; b++){ acc[a][b][0]=0.f; acc[a][b][1]=0.f; acc[a][b][2]=0.f; acc[a][b][3]=0.f; }

    for (int nt = 0; nt < 4; nt++){
        int node = i0 + nt * 16 + li;
        const float* hp = h + (size_t)node * 128 + lg * 8;
        s16x8 bfr[4];
#pragma unroll
        for (int kt = 0; kt < 4; kt++){
            float4 v0 = *(const float4*)(hp + kt * 32);
            float4 v1 = *(const float4*)(hp + kt * 32 + 4);
            s16x8 bf;
            bf[0]=(short)f2b(v0.x); bf[1]=(short)f2b(v0.y); bf[2]=(short)f2b(v0.z); bf[3]=(short)f2b(v0.w);
            bf[4]=(short)f2b(v1.x); bf[5]=(short)f2b(v1.y); bf[6]=(short)f2b(v1.z); bf[7]=(short)f2b(v1.w);
            bfr[kt] = bf;
        }
#pragma unroll
        for (int mtl = 0; mtl < 4; mtl++){
            int mt = w * 4 + mtl;
#pragma unroll
            for (int kt = 0; kt < 4; kt++){
                s16x8 af = *(const s16x8*)(W1p + (size_t)(mt * 4 + kt) * 512 + l * 8);
                acc[mtl][nt] = __builtin_amdgcn_mfma_f32_16x16x32_bf16(af, bfr[kt], acc[mtl][nt], 0, 0, 0);
            }
        }
    }
#pragma unroll
    for (int mtl = 0; mtl < 4; mtl++){
        int mt = w * 4 + mtl;
        int ccb = mt * 16 + lg * 4;   // 0..252, aligned 4
#pragma unroll
        for (int nt = 0; nt < 4; nt++){
            int node = i0 + nt * 16 + li;
            float b0=0.f,b1=0.f,b2=0.f,b3=0.f;
            if (ccb < 128){ float4 bb = *(const float4*)(be1 + ccb); b0=bb.x; b1=bb.y; b2=bb.z; b3=bb.w; }
            ushort o0 = f2b(acc[mtl][nt][0] + b0);
            ushort o1 = f2b(acc[mtl][nt][1] + b1);
            ushort o2 = f2b(acc[mtl][nt][2] + b2);
            ushort o3 = f2b(acc[mtl][nt][3] + b3);
            uint2 val = make_uint2((uint)o0 | ((uint)o1 << 16), (uint)o2 | ((uint)o3 << 16));
            ushort* dst = (ccb < 128) ? (A + (size_t)node * 128 + ccb)
                                      : (Bm + (size_t)node * 128 + (ccb - 128));
            *(uint2*)dst = val;
        }
    }
}

// ---------------------------------------------------------------------------
// Fused edge + node kernel. 8 nodes / 128 edges per block, 256 threads.
// ---------------------------------------------------------------------------
__global__ __launch_bounds__(256, 3) void egnn_fused(
    const float* __restrict__ h, const float* __restrict__ x,
    const int* __restrict__ edge_idx,
    const ushort* __restrict__ A, const ushort* __restrict__ Bm,
    const float* __restrict__ We1,
    const ushort* __restrict__ We2T, const float* __restrict__ be2,
    const ushort* __restrict__ Wc1T, const float* __restrict__ bc1,
    const float* __restrict__ Wc2,
    const ushort* __restrict__ Wn1T, const float* __restrict__ bn1,
    const ushort* __restrict__ Wn2T, const float* __restrict__ bn2,
    float* __restrict__ out, int BN)
{
    __shared__ ushort m_lds[EB * 128];      // t, then m (bf16, XOR-swizzled 16B blocks)
    __shared__ float  hsh[NB * 132];
    __shared__ ushort Ash[NB * 128];
    __shared__ float  msum[NB * 132];
    __shared__ ushort u_lds[16 * 128];
    __shared__ ushort w256sh[128];
    __shared__ float  sqd[EB];
    __shared__ float  xd[EB * 3];
    __shared__ float  cwvp[4][EB];
    __shared__ int    jgs[EB];

    const int tid = threadIdx.x;
    const int w = tid >> 6, l = tid & 63, lg = l >> 4, li = l & 15;
    const int i0 = blockIdx.x * NB;

    // ---- P0: stage h, A, w256, geometry ----
    {
        int r = tid >> 5, c = (tid & 31) * 4;
        *(float4*)&hsh[r * 132 + c] = *(const float4*)&h[(size_t)(i0 + r) * 128 + c];
        if (tid < 128){
            int rr = tid >> 4, cc = (tid & 15) * 8;
            *(s16x8*)&Ash[rr * 128 + cc] = *(const s16x8*)&A[(size_t)(i0 + rr) * 128 + cc];
        } else {
            int t2 = tid - 128;
            w256sh[t2] = f2b(We1[256 * 128 + t2]);
            s16x8 z; for (int e = 0; e < 8; e++) z[e] = 0;
            *(s16x8*)&u_lds[(8 + (t2 >> 4)) * 128 + (t2 & 15) * 8] = z;  // zero pad rows
        }
        if (tid < EB){
            int e = tid;
            int i = i0 + (e >> 4);
            int b = i / NN;
            int jl = edge_idx[(size_t)i * KN + (e & 15)];
            int j = b * NN + jl;
            jgs[e] = j;
            float d0 = x[i*3+0] - x[j*3+0];
            float d1 = x[i*3+1] - x[j*3+1];
            float d2 = x[i*3+2] - x[j*3+2];
            xd[e*3+0] = d0; xd[e*3+1] = d1; xd[e*3+2] = d2;
            sqd[e] = d0*d0 + d1*d1 + d2*d2;
        }
    }
    __syncthreads();

    // ---- P1: t = silu(A[i] + Bm[j] + sqd*We1[256]) -> m_lds (bf16, swizzled) ----
    {
        const int e0 = w * 32;
#pragma unroll
        for (int nt = 0; nt < 2; nt++){
            int edge = e0 + nt * 16 + li;
            int nodel = edge >> 4;
            int j = jgs[edge];
            float sq = sqd[edge];
#pragma unroll
            for (int kt = 0; kt < 4; kt++){
                int c8 = kt * 32 + lg * 8;
                s16x8 bm = *(const s16x8*)&Bm[(size_t)j * 128 + c8];
                s16x8 av = *(const s16x8*)&Ash[nodel * 128 + c8];
                s16x8 wv = *(const s16x8*)&w256sh[c8];
                s16x8 ov;
#pragma unroll
                for (int e = 0; e < 8; e++){
                    float t = b2f((ushort)av[e]) + b2f((ushort)bm[e]) + sq * b2f((ushort)wv[e]);
                    ov[e] = (short)f2b(silu_f(t));
                }
                int blk = (kt * 4 + lg) ^ (edge & 7);
                *(s16x8*)&m_lds[edge * 128 + blk * 8] = ov;
            }
        }
    }
    __syncthreads();

    // ---- GEMM1: m^T = We2^T @ t^T. wave w: m-cols 32w..32w+31 (mt 2w,2w+1), all 128 edges ----
    f32x4 acc[16];
#pragma unroll
    for (int q = 0; q < 16; q++){ acc[q][0]=0.f; acc[q][1]=0.f; acc[q][2]=0.f; acc[q][3]=0.f; }

#pragma unroll
    for (int kt = 0; kt < 4; kt++){
        s16x8 bfr[8];
#pragma unroll
        for (int nt = 0; nt < 8; nt++){
            int edge = nt * 16 + li;
            int blk = (kt * 4 + lg) ^ (edge & 7);
            bfr[nt] = *(const s16x8*)&m_lds[edge * 128 + blk * 8];
        }
#pragma unroll
        for (int mtl = 0; mtl < 2; mtl++){
            int mt = w * 2 + mtl;
            s16x8 af = *(const s16x8*)&We2T[(size_t)(mt * 4 + kt) * 512 + l * 8];
#pragma unroll
            for (int nt = 0; nt < 8; nt++)
                acc[mtl * 8 + nt] = __builtin_amdgcn_mfma_f32_16x16x32_bf16(af, bfr[nt], acc[mtl * 8 + nt], 0, 0, 0);
        }
    }
    __syncthreads();   // all waves done reading t before m overwrites

    // epilogue: m = silu(. + be2) -> m_lds ; then msum (own cols)
#pragma unroll
    for (int mtl = 0; mtl < 2; mtl++){
        int mt = w * 2 + mtl;
        int cb = mt * 16 + lg * 4;
        float4 bb = *(const float4*)&be2[cb];
#pragma unroll
        for (int nt = 0; nt < 8; nt++){
            int edge = nt * 16 + li;
            f32x4 a = acc[mtl * 8 + nt];
            ushort o0 = f2b(silu_f(a[0] + bb.x));
            ushort o1 = f2b(silu_f(a[1] + bb.y));
            ushort o2 = f2b(silu_f(a[2] + bb.z));
            ushort o3 = f2b(silu_f(a[3] + bb.w));
            int blk = (mt * 2 + (lg >> 1)) ^ (edge & 7);
            uint2 val = make_uint2((uint)o0 | ((uint)o1 << 16), (uint)o2 | ((uint)o3 << 16));
            *(uint2*)&m_lds[edge * 128 + blk * 8 + (lg & 1) * 4] = val;
        }
    }
    {   // msum over each node's 16 edges, this wave's 32 cols
        int nodel = l >> 3;
        int c0 = w * 32 + (l & 7) * 4;
        float s0=0.f, s1=0.f, s2=0.f, s3=0.f;
#pragma unroll
        for (int k = 0; k < 16; k++){
            int edge = nodel * 16 + k;
            int blk = (c0 >> 3) ^ (edge & 7);
            uint2 v = *(uint2*)&m_lds[edge * 128 + blk * 8 + (c0 & 4)];
            s0 += b2f((ushort)(v.x & 0xffff)); s1 += b2f((ushort)(v.x >> 16));
            s2 += b2f((ushort)(v.y & 0xffff)); s3 += b2f((ushort)(v.y >> 16));
        }
        float4 sv = make_float4(s0, s1, s2, s3);
        *(float4*)&msum[nodel * 132 + c0] = sv;
    }
    __syncthreads();

    // ---- GEMM2: c1^T = Wc1^T @ m^T, epilogue folds silu + dot(Wc2) into cw ----
#pragma unroll
    for (int q = 0; q < 16; q++){ acc[q][0]=0.f; acc[q][1]=0.f; acc[q][2]=0.f; acc[q][3]=0.f; }
#pragma unroll
    for (int kt = 0; kt < 4; kt++){
        s16x8 bfr[8];
#pragma unroll
        for (int nt = 0; nt < 8; nt++){
            int edge = nt * 16 + li;
            int blk = (kt * 4 + lg) ^ (edge & 7);
            bfr[nt] = *(const s16x8*)&m_lds[edge * 128 + blk * 8];
        }
#pragma unroll
        for (int mtl = 0; mtl < 2; mtl++){
            int mt = w * 2 + mtl;
            s16x8 af = *(const s16x8*)&Wc1T[(size_t)(mt * 4 + kt) * 512 + l * 8];
#pragma unroll
            for (int nt = 0; nt < 8; nt++)
                acc[mtl * 8 + nt] = __builtin_amdgcn_mfma_f32_16x16x32_bf16(af, bfr[nt], acc[mtl * 8 + nt], 0, 0, 0);
        }
    }
    {
        float cwp[8];
#pragma unroll
        for (int nt = 0; nt < 8; nt++) cwp[nt] = 0.f;
#pragma unroll
        for (int mtl = 0; mtl < 2; mtl++){
            int mt = w * 2 + mtl;
            int cb = mt * 16 + lg * 4;
            float4 bc = *(const float4*)&bc1[cb];
            float4 wc = *(const float4*)&Wc2[cb];
#pragma unroll
            for (int nt = 0; nt < 8; nt++){
                f32x4 a = acc[mtl * 8 + nt];
                cwp[nt] += silu_f(a[0] + bc.x) * wc.x + silu_f(a[1] + bc.y) * wc.y
                         + silu_f(a[2] + bc.z) * wc.z + silu_f(a[3] + bc.w) * wc.w;
            }
        }
#pragma unroll
        for (int nt = 0; nt < 8; nt++){
            float v = cwp[nt];
            v += __shfl_xor(v, 16);
            v += __shfl_xor(v, 32);
            if (lg == 0) cwvp[w][nt * 16 + li] = v;
        }
    }

    // ---- GEMM3': u^T = Wn1^T @ [h|msum]^T  (N = 8 nodes, wave w: u-cols 32w..32w+31) ----
    {
        f32x4 acc3[2];
        acc3[0][0]=0.f; acc3[0][1]=0.f; acc3[0][2]=0.f; acc3[0][3]=0.f;
        acc3[1][0]=0.f; acc3[1][1]=0.f; acc3[1][2]=0.f; acc3[1][3]=0.f;
#pragma unroll
        for (int kt = 0; kt < 8; kt++){
            int node = li & 7;
            const float* bp = (kt < 4) ? (hsh + node * 132 + kt * 32 + lg * 8)
                                       : (msum + node * 132 + (kt - 4) * 32 + lg * 8);
            float4 v0 = *(const float4*)bp;
            float4 v1 = *(const float4*)(bp + 4);
            s16x8 bf;
            bf[0]=(short)f2b(v0.x); bf[1]=(short)f2b(v0.y); bf[2]=(short)f2b(v0.z); bf[3]=(short)f2b(v0.w);
            bf[4]=(short)f2b(v1.x); bf[5]=(short)f2b(v1.y); bf[6]=(short)f2b(v1.z); bf[7]=(short)f2b(v1.w);
#pragma unroll
            for (int mtl = 0; mtl < 2; mtl++){
                int mt = w * 2 + mtl;
                s16x8 af = *(const s16x8*)&Wn1T[(size_t)(mt * 8 + kt) * 512 + l * 8];
                acc3[mtl] = __builtin_amdgcn_mfma_f32_16x16x32_bf16(af, bf, acc3[mtl], 0, 0, 0);
            }
        }
#pragma unroll
        for (int mtl = 0; mtl < 2; mtl++){
            int mt = w * 2 + mtl;
            int cb = mt * 16 + lg * 4;
            float4 bb = *(const float4*)&bn1[cb];
            if (li < 8){
                f32x4 a = acc3[mtl];
                ushort o0 = f2b(silu_f(a[0] + bb.x));
                ushort o1 = f2b(silu_f(a[1] + bb.y));
                ushort o2 = f2b(silu_f(a[2] + bb.z));
                ushort o3 = f2b(silu_f(a[3] + bb.w));
                int blk = (mt * 2 + (lg >> 1)) ^ (li & 7);
                uint2 val = make_uint2((uint)o0 | ((uint)o1 << 16), (uint)o2 | ((uint)o3 << 16));
                *(uint2*)&u_lds[li * 128 + blk * 8 + (lg & 1) * 4] = val;
            }
        }
    }
    __syncthreads();

    // ---- x update (cwvp complete) ----
    if (tid < 24){
        int nd = tid / 3, d = tid % 3;
        float s = 0.f;
#pragma unroll
        for (int k = 0; k < 16; k++){
            int e = nd * 16 + k;
            s += xd[e * 3 + d] * (cwvp[0][e] + cwvp[1][e] + cwvp[2][e] + cwvp[3][e]);
        }
        int i = i0 + nd;
        out[(size_t)BN * H + (size_t)i * 3 + d] = x[(size_t)i * 3 + d] + s * (1.0f / 16.0f);
    }

    // ---- GEMM4': h_new^T = Wn2^T @ u^T, epilogue += bn2 + h ----
    {
        f32x4 acc4[2];
        acc4[0][0]=0.f; acc4[0][1]=0.f; acc4[0][2]=0.f; acc4[0][3]=0.f;
        acc4[1][0]=0.f; acc4[1][1]=0.f; acc4[1][2]=0.f; acc4[1][3]=0.f;
#pragma unroll
        for (int kt = 0; kt < 4; kt++){
            int blk = (kt * 4 + lg) ^ (li & 7);
            s16x8 bf = *(const s16x8*)&u_lds[li * 128 + blk * 8];
#pragma unroll
            for (int mtl = 0; mtl < 2; mtl++){
                int mt = w * 2 + mtl;
                s16x8 af = *(const s16x8*)&Wn2T[(size_t)(mt * 4 + kt) * 512 + l * 8];
                acc4[mtl] = __builtin_amdgcn_mfma_f32_16x16x32_bf16(af, bf, acc4[mtl], 0, 0, 0);
            }
        }
#pragma unroll
        for (int mtl = 0; mtl < 2; mtl++){
            int mt = w * 2 + mtl;
            int cb = mt * 16 + lg * 4;
            if (li < 8){
                float4 bb = *(const float4*)&bn2[cb];
                float4 hv = *(const float4*)&hsh[li * 132 + cb];
                f32x4 a = acc4[mtl];
                float4 o;
                o.x = a[0] + bb.x + hv.x;
                o.y = a[1] + bb.y + hv.y;
                o.z = a[2] + bb.z + hv.z;
                o.w = a[3] + bb.w + hv.w;
                *(float4*)&out[(size_t)(i0 + li) * 128 + cb] = o;
            }
        }
    }
}

extern "C" void kernel_launch(void* const* d_in, const int* in_sizes, int n_in,
                              void* d_out, int out_size, void* d_ws, size_t ws_size,
                              hipStream_t stream) {
    const float* h        = (const float*)d_in[0];
    const float* x        = (const float*)d_in[1];
    const int*   edge_idx = (const int*)d_in[2];
    const float* We1      = (const float*)d_in[3];
    const float* be1      = (const float*)d_in[4];
    const float* We2      = (const float*)d_in[5];
    const float* be2      = (const float*)d_in[6];
    const float* Wc1      = (const float*)d_in[7];
    const float* bc1      = (const float*)d_in[8];
    const float* Wc2      = (const float*)d_in[9];
    const float* Wn1      = (const float*)d_in[10];
    const float* bn1      = (const float*)d_in[11];
    const float* Wn2      = (const float*)d_in[12];
    const float* bn2      = (const float*)d_in[13];
    float* out = (float*)d_out;

    const int BN = in_sizes[0] / H;   // 32768

    ushort* A    = (ushort*)d_ws;
    ushort* Bm   = A + (size_t)BN * H;
    ushort* We2T = Bm + (size_t)BN * H;
    ushort* Wc1T = We2T + 32 * 512;
    ushort* Wn1T = Wc1T + 32 * 512;
    ushort* Wn2T = Wn1T + 64 * 512;
    ushort* W1pT = Wn2T + 32 * 512;

    pack_all<<<56, 256, 0, stream>>>(We2, Wc1, Wn1, Wn2, We1,
                                     We2T, Wc1T, Wn1T, Wn2T, W1pT);
    precompute_mfma<<<BN / 64, 256, 0, stream>>>(h, be1, W1pT, A, Bm);
    egnn_fused<<<BN / NB, 256, 0, stream>>>(h, x, edge_idx, A, Bm, We1,
                                            We2T, be2, Wc1T, bc1, Wc2,
                                            Wn1T, bn1, Wn2T, bn2, out, BN);
}